// Round 13
// baseline (214.886 us; speedup 1.0000x reference)
//
#include <hip/hip_runtime.h>

// ---------------------------------------------------------------------------
// GCN 2-layer pipeline:
//   h1 = relu(spmm(A, x@W1) + b1); out = relu(spmm(A, h1@W2) + b2)
// CSR build (atomic-free radix structure):
//   histgemm: per-binblock bucket hist ∥ gemm1 (MFMA) ∥ Wt2 prep
//   scanA: column scan -> deterministic per-(blk,bucket) offsets + colsum
//   bin: LDS counting sort (bucket bases recomputed in-register from colsum;
//        block 0 publishes bbase); no global atomics
//   final_scatter (1024 thr): per-bucket row sort -> rowptr + csr
// agg128: full wave/row, 2 cols/lane, 16/4/1 unroll ladder.
// agg64: 4 rows/wave, quarter-wave per row, 16/8/1 unroll ladder.
// Lessons: R5/R9 no gather+MFMA fusion / LDS-atomic accum; R10 keep sW in
// LDS; R8 global reserve atomics serialize; R11/R12 unroll depth must match
// the degree distribution (mean 18).
// ---------------------------------------------------------------------------

typedef unsigned int uint;
typedef unsigned short ushort;
typedef unsigned char uchar;
typedef __attribute__((ext_vector_type(8))) short bf16x8;
typedef __attribute__((ext_vector_type(4))) float f32x4;

#define RPB_SHIFT 8
#define RPB 256          // rows per bucket
#define MAXB 512         // max buckets (N <= 131072)
#define CH 2048          // edges per bin-block

__device__ __forceinline__ ushort f2bf(float f) {   // RNE float->bf16
    uint u = __float_as_uint(f);
    u += 0x7fffu + ((u >> 16) & 1u);
    return (ushort)(u >> 16);
}
__device__ __forceinline__ float bflo(uint p) { return __uint_as_float(p << 16); }
__device__ __forceinline__ float bfhi(uint p) { return __uint_as_float(p & 0xffff0000u); }

__device__ __forceinline__ int wscan(int v, int lane) {
    #pragma unroll
    for (int off = 1; off < 64; off <<= 1) {
        int u = __shfl_up(v, off);
        if (lane >= off) v += u;
    }
    return v;
}

// ---------------- K1: per-binblock hist ∥ gemm1 ∥ Wt2 prep ----------------
__global__ __launch_bounds__(256) void histgemm(
        const int* __restrict__ row, int* __restrict__ partial, int E, int BB,
        const float* __restrict__ xa, const float* __restrict__ xb, int na,
        const float* __restrict__ W1, ushort* __restrict__ sup1, int M,
        const float* __restrict__ W2, ushort* __restrict__ Wt2, int gblocks) {
    __shared__ char smem[52224];
    int t = threadIdx.x;
    int bid = blockIdx.x;

    if (bid < BB) {
        int* h = (int*)smem;
        h[t] = 0; h[t + 256] = 0;
        __syncthreads();
        int e0 = bid * CH;
        #pragma unroll
        for (int k = 0; k < 8; ++k) {
            int e = e0 + (k << 8) + t;
            if (e < E) atomicAdd(&h[row[e] >> RPB_SHIFT], 1);
        }
        __syncthreads();
        partial[(size_t)bid * MAXB + t]       = h[t];
        partial[(size_t)bid * MAXB + 256 + t] = h[t + 256];
        return;
    }
    if (bid >= BB + gblocks) {
        int g = (bid - BB - gblocks) * 256 + t;
        if (g < 8192) { int k = g >> 6, n = g & 63; Wt2[n * 128 + k] = f2bf(W2[g]); }
        return;
    }

    // ---- gemm1: 64 rows/block, 4 waves, sW staged from W1 (transpose) ----
    ushort (*sX)[136] = (ushort(*)[136])smem;            // 17408B
    ushort (*sW)[136] = (ushort(*)[136])(smem + 17408);  // 34816B
    int row0 = (bid - BB) * 64;

    #pragma unroll
    for (int i = 0; i < 16; ++i) {           // sW[n][k] = bf16(W1[k][n])
        int idx = i * 256 + t;               // 0..4095
        int k = idx >> 5, n4 = (idx & 31) << 2;
        float4 v = *(const float4*)(W1 + k * 128 + n4);
        sW[n4 + 0][k] = f2bf(v.x); sW[n4 + 1][k] = f2bf(v.y);
        sW[n4 + 2][k] = f2bf(v.z); sW[n4 + 3][k] = f2bf(v.w);
    }
    #pragma unroll
    for (int i = 0; i < 8; ++i) {
        int idx = i * 256 + t;
        int r = idx >> 5, c4 = (idx & 31) << 2;
        int gr = row0 + r;
        float4 v = make_float4(0.f, 0.f, 0.f, 0.f);
        if (gr < M) {
            const float* src = (gr < na) ? (xa + (size_t)gr * 128)
                                         : (xb + (size_t)(gr - na) * 128);
            v = *(const float4*)(src + c4);
        }
        uint2 p;
        p.x = (uint)f2bf(v.x) | ((uint)f2bf(v.y) << 16);
        p.y = (uint)f2bf(v.z) | ((uint)f2bf(v.w) << 16);
        *(uint2*)(&sX[r][c4]) = p;
    }
    __syncthreads();

    int lane = t & 63, w = t >> 6;
    int r0 = w << 4;
    int lrow = lane & 15, lk = (lane >> 4) << 3;
    f32x4 acc[8];
    #pragma unroll
    for (int n = 0; n < 8; ++n) acc[n] = (f32x4){0.f, 0.f, 0.f, 0.f};
    #pragma unroll
    for (int ks = 0; ks < 4; ++ks) {
        bf16x8 a = *(const bf16x8*)(&sX[r0 + lrow][ks * 32 + lk]);
        #pragma unroll
        for (int n = 0; n < 8; ++n) {
            bf16x8 b = *(const bf16x8*)(&sW[n * 16 + lrow][ks * 32 + lk]);
            acc[n] = __builtin_amdgcn_mfma_f32_16x16x32_bf16(a, b, acc[n], 0, 0, 0);
        }
    }
    __syncthreads();
    #pragma unroll
    for (int n = 0; n < 8; ++n)
        #pragma unroll
        for (int r = 0; r < 4; ++r)
            sX[r0 + ((lane >> 4) << 2) + r][n * 16 + lrow] = f2bf(acc[n][r]);
    __syncthreads();
    #pragma unroll
    for (int i = 0; i < 4; ++i) {
        int idx = i * 256 + t;
        int r = idx >> 4, c8 = (idx & 15) << 3;
        int gr = row0 + r;
        if (gr < M)
            *(uint4*)(sup1 + (size_t)gr * 128 + c8) = *(const uint4*)(&sX[r][c8]);
    }
}

// ---------------- K2: column scan of partial (one block per bucket) --------
__global__ __launch_bounds__(256) void scanA(int* __restrict__ partial,
                                             int* __restrict__ colsum, int BB) {
    __shared__ int wsum[4];
    int b = blockIdx.x;
    int t = threadIdx.x, lane = t & 63, w = t >> 6;
    int carry = 0;
    for (int c0 = 0; c0 < BB; c0 += 256) {
        int i = c0 + t;
        int v = (i < BB) ? partial[(size_t)i * MAXB + b] : 0;
        int incl = wscan(v, lane);
        if (lane == 63) wsum[w] = incl;
        __syncthreads();
        int woff = 0, tot = 0;
        #pragma unroll
        for (int k = 0; k < 4; ++k) { int x = wsum[k]; tot += x; if (k < w) woff += x; }
        if (i < BB) partial[(size_t)i * MAXB + b] = incl - v + woff + carry;
        carry += tot;
        __syncthreads();
    }
    if (t == 0) colsum[b] = carry;
}

// ---------------- K3: bin — LDS counting sort, bases from colsum ------------
// Bucket bases recomputed per-block in registers (thread t owns buckets
// 2t, 2t+1); block 0 publishes bbase for final_scatter. No global atomics.
__global__ __launch_bounds__(256) void bin_kernel(
        const int* __restrict__ row, const int* __restrict__ col,
        const float* __restrict__ val, const int* __restrict__ colsum,
        int* __restrict__ bbase, const int* __restrict__ partial,
        uchar* __restrict__ brow8, int2* __restrict__ bcolval, int E) {
    __shared__ uchar srow8[CH];      //  2KB
    __shared__ ushort sbkt[CH];      //  4KB
    __shared__ int2 scv[CH];         // 16KB
    __shared__ int hist[MAXB];       //  2KB (becomes g2)
    __shared__ int cur[MAXB];        //  2KB
    __shared__ int wsum[4];
    int t = threadIdx.x, lane = t & 63, w = t >> 6;
    int blk = blockIdx.x;

    // bucket bases (exclusive scan of colsum) — registers only
    int cc0 = colsum[2 * t], cc1 = colsum[2 * t + 1];
    int bs = cc0 + cc1;
    int bv = wscan(bs, lane);
    if (lane == 63) wsum[w] = bv;
    hist[t] = 0; hist[t + 256] = 0;
    __syncthreads();
    int bwoff = 0;
    #pragma unroll
    for (int k = 0; k < 4; ++k) if (k < w) bwoff += wsum[k];
    int bex0 = bv + bwoff - bs;        // bbase[2t]
    int bex1 = bex0 + cc0;             // bbase[2t+1]
    if (blk == 0) {
        bbase[2 * t] = bex0;
        bbase[2 * t + 1] = bex1;
        if (t == 0) bbase[MAXB] = E;
    }

    int e0 = blk * CH;
    int rr[8]; int2 rc[8];
    #pragma unroll
    for (int k = 0; k < 8; ++k) {
        int e = e0 + (k << 8) + t;
        if (e < E) {
            rr[k] = row[e];
            rc[k] = make_int2(col[e], __float_as_int(val[e]));
            atomicAdd(&hist[rr[k] >> RPB_SHIFT], 1);
        } else rr[k] = -1;
    }
    __syncthreads();

    int h0 = hist[2 * t], h1 = hist[2 * t + 1];
    int s = h0 + h1;
    int v = wscan(s, lane);
    if (lane == 63) wsum[w] = v;
    __syncthreads();
    int woff = 0, tot = 0;
    #pragma unroll
    for (int k = 0; k < 4; ++k) { int x = wsum[k]; tot += x; if (k < w) woff += x; }
    int lb0 = v + woff - s;
    int lb1 = lb0 + h0;
    cur[2 * t] = lb0; cur[2 * t + 1] = lb1;
    hist[2 * t]     = bex0 + partial[(size_t)blk * MAXB + 2 * t]     - lb0;
    hist[2 * t + 1] = bex1 + partial[(size_t)blk * MAXB + 2 * t + 1] - lb1;
    __syncthreads();

    #pragma unroll
    for (int k = 0; k < 8; ++k) {
        if (rr[k] >= 0) {
            int b = rr[k] >> RPB_SHIFT;
            int p = atomicAdd(&cur[b], 1);
            srow8[p] = (uchar)(rr[k] & (RPB - 1));
            sbkt[p]  = (ushort)b;
            scv[p]   = rc[k];
        }
    }
    __syncthreads();

    for (int i = t; i < tot; i += 256) {
        int b = sbkt[i];
        int g = hist[b] + i;
        brow8[g]   = srow8[i];
        bcolval[g] = scv[i];
    }
}

// ---------------- K4: final_scatter (1024 threads, uchar rows) ---------------
__global__ __launch_bounds__(1024) void final_scatter(
        const int* __restrict__ bbase, const uchar* __restrict__ brow8,
        const int2* __restrict__ bcolval, int* __restrict__ rowptr,
        int2* __restrict__ csr, int N, int E) {
    __shared__ int h[RPB];
    __shared__ int cur[RPB];
    __shared__ int wsum[4];
    int b = blockIdx.x;
    int t = threadIdx.x;
    int lane = t & 63, w = t >> 6;
    int base = bbase[b], end = bbase[b + 1];
    int row0 = b << RPB_SHIFT;

    if (t < RPB) h[t] = 0;
    __syncthreads();
    for (int i = base + t; i < end; i += 1024)
        atomicAdd(&h[brow8[i]], 1);
    __syncthreads();

    int a = 0, v = 0;
    if (t < RPB) {
        a = h[t];
        v = wscan(a, lane);
        if (lane == 63) wsum[w] = v;
    }
    __syncthreads();
    if (t < RPB) {
        int woff = 0;
        #pragma unroll
        for (int k = 0; k < 4; ++k) if (k < w) woff += wsum[k];
        int excl = v + woff - a;
        cur[t] = excl;
        int gr = row0 + t;
        if (gr < N) rowptr[gr] = base + excl;
    }
    if (b == 0 && t == 0) rowptr[N] = E;
    __syncthreads();

    for (int i = base + t; i < end; i += 1024) {
        int r = brow8[i];
        int p = atomicAdd(&cur[r], 1);
        csr[base + p] = bcolval[i];
    }
}

// ---------------- K6: gemm2: sup2[M,64](bf16) = h1[M,128](bf16) @ W2 -------
__global__ __launch_bounds__(256) void gemm_mfma64(
        const ushort* __restrict__ xa, const ushort* __restrict__ Wt,
        ushort* __restrict__ out, int M) {
    __shared__ ushort sX[64][136];
    __shared__ ushort sW[64][136];
    int t = threadIdx.x;
    int row0 = blockIdx.x * 64;

    #pragma unroll
    for (int i = 0; i < 4; ++i) {
        int idx = i * 256 + t;
        int n = idx >> 4, c8 = (idx & 15) << 3;
        *(uint4*)(&sW[n][c8]) = *(const uint4*)(Wt + n * 128 + c8);
    }
    #pragma unroll
    for (int i = 0; i < 4; ++i) {
        int idx = i * 256 + t;
        int r = idx >> 4, c8 = (idx & 15) << 3;
        int gr = row0 + r;
        uint4 v = make_uint4(0, 0, 0, 0);
        if (gr < M) v = *(const uint4*)(xa + (size_t)gr * 128 + c8);
        *(uint4*)(&sX[r][c8]) = v;
    }
    __syncthreads();

    int lane = t & 63, w = t >> 6;
    int r0 = w * 16;
    int lrow = lane & 15, lk = (lane >> 4) << 3;
    f32x4 acc[4];
    #pragma unroll
    for (int n = 0; n < 4; ++n) acc[n] = (f32x4){0.f, 0.f, 0.f, 0.f};

    #pragma unroll
    for (int ks = 0; ks < 4; ++ks) {
        bf16x8 a = *(const bf16x8*)(&sX[r0 + lrow][ks * 32 + lk]);
        #pragma unroll
        for (int n = 0; n < 4; ++n) {
            bf16x8 b = *(const bf16x8*)(&sW[n * 16 + lrow][ks * 32 + lk]);
            acc[n] = __builtin_amdgcn_mfma_f32_16x16x32_bf16(a, b, acc[n], 0, 0, 0);
        }
    }
    __syncthreads();
    #pragma unroll
    for (int n = 0; n < 4; ++n)
        #pragma unroll
        for (int r = 0; r < 4; ++r)
            sX[r0 + ((lane >> 4) << 2) + r][n * 16 + lrow] = f2bf(acc[n][r]);
    __syncthreads();
    #pragma unroll
    for (int i = 0; i < 2; ++i) {
        int idx = i * 256 + t;
        int r = idx >> 3, c8 = (idx & 7) << 3;
        int gr = row0 + r;
        if (gr < M)
            *(uint4*)(out + (size_t)gr * 64 + c8) = *(const uint4*)(&sX[r][c8]);
    }
}

// ---------------- K5: agg128: full wave/row, 16/4/1 unroll, bf16 out --------
__global__ __launch_bounds__(256) void agg_kernel128(
        const ushort* __restrict__ sup, const int* __restrict__ rowptr,
        const int2* __restrict__ csr, const float* __restrict__ bias,
        ushort* __restrict__ out, int M) {
    int wid = (blockIdx.x * 256 + threadIdx.x) >> 6;
    int lane = threadIdx.x & 63;
    if (wid >= M) return;
    int jb = __builtin_amdgcn_readfirstlane(rowptr[wid]);
    int je = __builtin_amdgcn_readfirstlane(rowptr[wid + 1]);
    const char* supb = (const char*)sup;
    uint loff = (uint)lane << 2;
    float a0x = 0.f, a0y = 0.f, a1x = 0.f, a1y = 0.f;
    float a2x = 0.f, a2y = 0.f, a3x = 0.f, a3y = 0.f;
    int j = jb;
    for (; j + 16 <= je; j += 16) {
        int2 c[16];
        #pragma unroll
        for (int u = 0; u < 16; ++u) c[u] = csr[j + u];
        uint sv[16];
        #pragma unroll
        for (int u = 0; u < 16; ++u)
            sv[u] = *(const uint*)(supb + ((((uint)c[u].x) << 8) | loff));
        #pragma unroll
        for (int u = 0; u < 16; ++u) {
            float v = __int_as_float(c[u].y);
            float lo = bflo(sv[u]), hi = bfhi(sv[u]);
            switch (u & 3) {
                case 0: a0x = fmaf(v, lo, a0x); a0y = fmaf(v, hi, a0y); break;
                case 1: a1x = fmaf(v, lo, a1x); a1y = fmaf(v, hi, a1y); break;
                case 2: a2x = fmaf(v, lo, a2x); a2y = fmaf(v, hi, a2y); break;
                default: a3x = fmaf(v, lo, a3x); a3y = fmaf(v, hi, a3y); break;
            }
        }
    }
    for (; j + 4 <= je; j += 4) {
        int2 c[4];
        #pragma unroll
        for (int u = 0; u < 4; ++u) c[u] = csr[j + u];
        uint sv[4];
        #pragma unroll
        for (int u = 0; u < 4; ++u)
            sv[u] = *(const uint*)(supb + ((((uint)c[u].x) << 8) | loff));
        #pragma unroll
        for (int u = 0; u < 4; ++u) {
            float v = __int_as_float(c[u].y);
            if (u & 1) { a1x = fmaf(v, bflo(sv[u]), a1x); a1y = fmaf(v, bfhi(sv[u]), a1y); }
            else       { a0x = fmaf(v, bflo(sv[u]), a0x); a0y = fmaf(v, bfhi(sv[u]), a0y); }
        }
    }
    for (; j < je; ++j) {
        int2 cc = csr[j];
        uint sv = *(const uint*)(supb + ((((uint)cc.x) << 8) | loff));
        float v = __int_as_float(cc.y);
        a0x = fmaf(v, bflo(sv), a0x); a0y = fmaf(v, bfhi(sv), a0y);
    }
    float2 b = *(const float2*)(bias + (lane << 1));
    float hx = fmaxf(a0x + a1x + a2x + a3x + b.x, 0.f);
    float hy = fmaxf(a0y + a1y + a2y + a3y + b.y, 0.f);
    uint p = (uint)f2bf(hx) | ((uint)f2bf(hy) << 16);
    *(uint*)(out + ((size_t)wid << 7) + (lane << 1)) = p;
}

// ---------------- K7: agg64: 4 rows/wave, quarter per row, 16/8/1 -----------
__global__ __launch_bounds__(256) void agg_kernel64(
        const ushort* __restrict__ sup, const int* __restrict__ rowptr,
        const int2* __restrict__ csr, const float* __restrict__ bias,
        float* __restrict__ out, int M) {
    int t = threadIdx.x;
    int lane = t & 63, wv = t >> 6;
    int q = lane >> 4, ql = lane & 15;
    int wid = blockIdx.x * 16 + wv * 4 + q;   // 16 rows per block
    if (wid >= M) return;
    int jb = rowptr[wid], je = rowptr[wid + 1];
    const char* supb = (const char*)sup;
    uint loff = (uint)ql << 3;
    float s0 = 0.f, s1 = 0.f, s2 = 0.f, s3 = 0.f;
    float t0 = 0.f, t1 = 0.f, t2 = 0.f, t3 = 0.f;
    int j = jb;
    for (; j + 16 <= je; j += 16) {
        int2 c[16];
        #pragma unroll
        for (int u = 0; u < 16; ++u) c[u] = csr[j + u];
        uint2 g[16];
        #pragma unroll
        for (int u = 0; u < 16; ++u)
            g[u] = *(const uint2*)(supb + ((((uint)c[u].x) << 7) | loff));
        #pragma unroll
        for (int u = 0; u < 16; ++u) {
            float v = __int_as_float(c[u].y);
            if (u & 1) {
                t0 = fmaf(v, bflo(g[u].x), t0); t1 = fmaf(v, bfhi(g[u].x), t1);
                t2 = fmaf(v, bflo(g[u].y), t2); t3 = fmaf(v, bfhi(g[u].y), t3);
            } else {
                s0 = fmaf(v, bflo(g[u].x), s0); s1 = fmaf(v, bfhi(g[u].x), s1);
                s2 = fmaf(v, bflo(g[u].y), s2); s3 = fmaf(v, bfhi(g[u].y), s3);
            }
        }
    }
    for (; j + 8 <= je; j += 8) {
        int2 c[8];
        #pragma unroll
        for (int u = 0; u < 8; ++u) c[u] = csr[j + u];
        uint2 g[8];
        #pragma unroll
        for (int u = 0; u < 8; ++u)
            g[u] = *(const uint2*)(supb + ((((uint)c[u].x) << 7) | loff));
        #pragma unroll
        for (int u = 0; u < 8; ++u) {
            float v = __int_as_float(c[u].y);
            if (u & 1) {
                t0 = fmaf(v, bflo(g[u].x), t0); t1 = fmaf(v, bfhi(g[u].x), t1);
                t2 = fmaf(v, bflo(g[u].y), t2); t3 = fmaf(v, bfhi(g[u].y), t3);
            } else {
                s0 = fmaf(v, bflo(g[u].x), s0); s1 = fmaf(v, bfhi(g[u].x), s1);
                s2 = fmaf(v, bflo(g[u].y), s2); s3 = fmaf(v, bfhi(g[u].y), s3);
            }
        }
    }
    for (; j < je; ++j) {
        int2 c = csr[j];
        uint2 g = *(const uint2*)(supb + ((((uint)c.x) << 7) | loff));
        float v = __int_as_float(c.y);
        s0 = fmaf(v, bflo(g.x), s0); s1 = fmaf(v, bfhi(g.x), s1);
        s2 = fmaf(v, bflo(g.y), s2); s3 = fmaf(v, bfhi(g.y), s3);
    }
    s0 += t0; s1 += t1; s2 += t2; s3 += t3;
    float4 b = *(const float4*)(bias + (ql << 2));
    float4 o = make_float4(fmaxf(s0 + b.x, 0.f), fmaxf(s1 + b.y, 0.f),
                           fmaxf(s2 + b.z, 0.f), fmaxf(s3 + b.w, 0.f));
    *(float4*)(out + ((size_t)wid << 6) + (ql << 2)) = o;
}

// ---------------- launch ----------------

extern "C" void kernel_launch(void* const* d_in, const int* in_sizes, int n_in,
                              void* d_out, int out_size, void* d_ws, size_t ws_size,
                              hipStream_t stream) {
    const int*   ei        = (const int*)d_in[0];     // [2, E]
    const float* vals      = (const float*)d_in[1];   // [E]
    const float* emb_node  = (const float*)d_in[2];   // [NN, 128]
    const float* emb_attri = (const float*)d_in[3];   // [NA, 128]
    const float* W1        = (const float*)d_in[4];   // [128, 128]
    const float* b1        = (const float*)d_in[5];   // [128]
    const float* W2        = (const float*)d_in[6];   // [128, 64]
    const float* b2        = (const float*)d_in[7];   // [64]

    const int E  = in_sizes[1];
    const int NN = in_sizes[2] / 128;
    const int NA = in_sizes[3] / 128;
    const int N  = NN + NA;
    const int nbuckets = (N + RPB - 1) >> RPB_SHIFT;   // <= 512

    const int* row = ei;
    const int* col = ei + E;

    int gblocks = (N + 63) / 64;
    int ablocks = (N + 3) / 4;
    int BB = (E + CH - 1) / CH;

    // Workspace (~77 MiB). sup reused by both layers; bcolval/brow8 alias the
    // h1 slot (dead until agg128 writes it).
    char*  ws   = (char*)d_ws;
    size_t A    = 512;
    size_t Ss   = (((size_t)N * 128 * sizeof(ushort)) + A - 1) / A * A;   // sup bf16
    size_t Sh   = (((size_t)N * 128 * sizeof(ushort)) + A - 1) / A * A;   // h1 bf16 / bin slot
    size_t csrB = (((size_t)E * sizeof(int2))         + A - 1) / A * A;
    size_t rpB  = (((size_t)(N + 1) * sizeof(int))    + A - 1) / A * A;
    size_t cvB  = (((size_t)E * sizeof(int2)) + A - 1) / A * A;

    ushort* sup    = (ushort*)ws;
    ushort* h1     = (ushort*)(ws + Ss);
    int2*   bcolval= (int2*)(ws + Ss);                   // aliases h1 (16MB)
    uchar*  brow8  = (uchar*)(ws + Ss + cvB);            // aliases h1 (+2MB <= 28MB)
    int2*   csr    = (int2*)(ws + Ss + Sh);
    int*    rowptr = (int*)(ws + Ss + Sh + csrB);
    char*   meta   = ws + Ss + Sh + csrB + rpB;
    int*    bbase  = (int*)meta;                          // 513 ints
    int*    colsum = (int*)(meta + 2560);                 // 512 ints
    ushort* Wt2    = (ushort*)(meta + 5120);              // 16 KB
    int*    partial= (int*)(meta + 5120 + 16384 + 512);   // BB*MAXB ints (~2MB)

    // 1. per-binblock hist + gemm1 + Wt2 prep
    histgemm<<<BB + gblocks + 32, 256, 0, stream>>>(row, partial, E, BB,
                                                    emb_node, emb_attri, NN,
                                                    W1, sup, N, W2, Wt2, gblocks);
    // 2. column scan: per-(blk,bucket) offsets + colsum
    scanA<<<MAXB, 256, 0, stream>>>(partial, colsum, BB);
    // 3. bin: LDS counting sort; bases from colsum (block 0 publishes bbase)
    bin_kernel<<<BB, 256, 0, stream>>>(row, col, vals, colsum, bbase, partial,
                                       brow8, bcolval, E);
    // 4. per-bucket row sort -> rowptr + csr
    final_scatter<<<nbuckets, 1024, 0, stream>>>(bbase, brow8, bcolval, rowptr,
                                                 csr, N, E);
    // 5. layer-1 aggregation
    agg_kernel128<<<ablocks, 256, 0, stream>>>(sup, rowptr, csr, b1, h1, N);
    // 6. layer-2 GEMM
    gemm_mfma64<<<gblocks, 256, 0, stream>>>(h1, Wt2, sup, N);
    // 7. layer-2 aggregation
    agg_kernel64<<<(N + 15) / 16, 256, 0, stream>>>(sup, rowptr, csr, b2, (float*)d_out, N);
}